// Round 1
// baseline (3617.078 us; speedup 1.0000x reference)
//
#include <hip/hip_runtime.h>
#include <hip/hip_bf16.h>
#include <math.h>

typedef unsigned int u32;
typedef unsigned short u16;
typedef __attribute__((ext_vector_type(8))) short short8;
typedef __attribute__((ext_vector_type(4))) float f32x4;

#define PI_F 3.14159265358979f
#define B_   512
#define T_   256
#define DIN  128
#define H_   256
#define G4   1024
#define F_   64
#define E_   320
#define DM   384
#define NL1  512
#define NACT 8
#define KMLP 394

__device__ __forceinline__ float b2f(u16 h) {
  union { u32 u; float f; } v; v.u = ((u32)h) << 16; return v.f;
}
__device__ __forceinline__ u16 f2b(float f) {
  union { float f; u32 u; } v; v.f = f;
  u32 r = (v.u + 0x7FFFu + ((v.u >> 16) & 1u)) >> 16;
  return (u16)r;
}
__device__ __forceinline__ float sigf(float x) { return 1.0f / (1.0f + __expf(-x)); }
__device__ __forceinline__ float tanhfast(float x) { return 2.0f / (1.0f + __expf(-2.0f * x)) - 1.0f; }
__device__ __forceinline__ float2 cmul(float2 a, float2 b) {
  return make_float2(a.x * b.x - a.y * b.y, a.x * b.y + a.y * b.x);
}
__device__ __forceinline__ float2 cadd(float2 a, float2 b) {
  return make_float2(a.x + b.x, a.y + b.y);
}

// ---------------------------------------------------------------------------
// prep1: x transpose+bf16, Wg=[W_ih|W_hh] bf16, zero hs[0], W1t, bb, uw, bkp,
// bvp, zero barrier counters
// ---------------------------------------------------------------------------
__global__ void k_prep1(const float* __restrict__ lstm_s,
                        const float* __restrict__ W_ih,
                        const float* __restrict__ W_hh,
                        const float* __restrict__ b_ih,
                        const float* __restrict__ b_hh,
                        const float* __restrict__ ipw,
                        const float* __restrict__ ipb,
                        const float* __restrict__ projb,
                        const float* __restrict__ qw,
                        const float* __restrict__ W1,
                        u16* __restrict__ xbf,
                        u16* __restrict__ hs,
                        u16* __restrict__ Wg,
                        float* __restrict__ bb,
                        float* __restrict__ W1t,
                        float* __restrict__ uw,
                        float* __restrict__ bkp,
                        float* __restrict__ bvp,
                        u32* __restrict__ cnt) {
  const int bid = blockIdx.x;
  const int tid = threadIdx.x;
  if (bid < 8192) {                       // lstm_s (B,T,128) -> xbf (T,B,128) bf16
    u32 u = (u32)bid * 256u + tid;        // < 2097152 uint4 units
    u32 c8 = u & 15u, b = (u >> 4) & 511u, t = u >> 13;
    const float* src = lstm_s + ((size_t)b * T_ + t) * DIN + c8 * 8;
    union { u16 h[8]; uint4 v; } tmp;
#pragma unroll
    for (int i = 0; i < 8; ++i) tmp.h[i] = f2b(src[i]);
    *(uint4*)(xbf + ((size_t)t * B_ + b) * DIN + c8 * 8) = tmp.v;
  } else if (bid < 8384) {                // Wg (1024 x 384) bf16
    u32 u = (u32)(bid - 8192) * 256u + tid;  // < 49152
    u32 c8 = u % 48u, r = u / 48u;
    const float* src = (c8 < 16) ? (W_ih + (size_t)r * DIN + c8 * 8)
                                 : (W_hh + (size_t)r * H_ + (c8 - 16) * 8);
    union { u16 h[8]; uint4 v; } tmp;
#pragma unroll
    for (int i = 0; i < 8; ++i) tmp.h[i] = f2b(src[i]);
    *(uint4*)(Wg + (size_t)r * 384 + c8 * 8) = tmp.v;
  } else if (bid < 8448) {                // zero hs[0]
    u32 u = (u32)(bid - 8384) * 256u + tid;  // < 16384
    ((uint4*)hs)[u] = make_uint4(0, 0, 0, 0);
  } else if (bid < 9236) {                // W1t[k][n] = W1[n][k]
    u32 u = (u32)(bid - 8448) * 256u + tid;  // < 201728
    u32 k = u / 512u, nn = u % 512u;
    W1t[u] = W1[(size_t)nn * KMLP + k];
  } else if (bid == 9236) {               // bb, cnt, uw
    for (int i = tid; i < 1024; i += 256) bb[i] = b_ih[i] + b_hh[i];
    for (int i = tid; i < 512; i += 256) cnt[i] = 0u;
    if (tid < 40) {
      float w0 = qw[tid * 3 + 0], w1 = qw[tid * 3 + 1], w2 = qw[tid * 3 + 2];
      float c0 = cosf(0.5f * w0), s0 = sinf(0.5f * w0);
      float c1 = cosf(0.5f * w1), s1 = sinf(0.5f * w1);
      float c2 = cosf(0.5f * w2), s2 = sinf(0.5f * w2);
      float2 e0m = make_float2(c0, -s0), e0p = make_float2(c0, s0);
      float2 e2m = make_float2(c2, -s2), e2p = make_float2(c2, s2);
      // T1 = RY(w1) @ RZ(w0)
      float2 t00 = make_float2(c1 * e0m.x, c1 * e0m.y);
      float2 t01 = make_float2(-s1 * e0p.x, -s1 * e0p.y);
      float2 t10 = make_float2(s1 * e0m.x, s1 * e0m.y);
      float2 t11 = make_float2(c1 * e0p.x, c1 * e0p.y);
      // U = RZ(w2) @ T1
      float2 u00 = cmul(e2m, t00), u01 = cmul(e2m, t01);
      float2 u10 = cmul(e2p, t10), u11 = cmul(e2p, t11);
      float* o = uw + tid * 8;
      o[0] = u00.x; o[1] = u00.y; o[2] = u01.x; o[3] = u01.y;
      o[4] = u10.x; o[5] = u10.y; o[6] = u11.x; o[7] = u11.y;
    }
  } else if (bid <= 9238) {               // bkp = Wk @ proj_b + bk
    int o = (bid - 9237) * 256 + tid;
    if (o < E_) {
      float acc = ipb[E_ + o];
      for (int e = 0; e < E_; ++e) acc += ipw[(size_t)(E_ + o) * E_ + e] * projb[e];
      bkp[o] = acc;
    }
  } else {                                // bvp = Wv @ proj_b + bv
    int o = (bid - 9239) * 256 + tid;
    if (o < E_) {
      float acc = ipb[2 * E_ + o];
      for (int e = 0; e < E_; ++e) acc += ipw[(size_t)(2 * E_ + o) * E_ + e] * projb[e];
      bvp[o] = acc;
    }
  }
}

// ---------------------------------------------------------------------------
// prep2: Wk' = Wk @ proj_W, Wv' = Wv @ proj_W  (each 320x256)
// ---------------------------------------------------------------------------
__global__ void k_prep2(const float* __restrict__ ipw, const float* __restrict__ projW,
                        float* __restrict__ Wkp, float* __restrict__ Wvp) {
  int bid = blockIdx.x, tid = threadIdx.x;
  int o = (bid < 320) ? bid : (bid - 320);
  const float* wrow = ipw + (size_t)((bid < 320 ? E_ : 2 * E_) + o) * E_;
  float acc = 0.f;
  for (int e = 0; e < E_; ++e) acc += wrow[e] * projW[(size_t)e * H_ + tid];
  (bid < 320 ? Wkp : Wvp)[(size_t)o * H_ + tid] = acc;
}

// ---------------------------------------------------------------------------
// prep3: WuT[e][j] = sum_o Wkp[o][j]*Wq[o][e];  Wovt[j][i] = sum_o Wo[i][o]*Wvp[o][j]
// plus bu, wd, dd, bov
// ---------------------------------------------------------------------------
__global__ void k_prep3(const float* __restrict__ ipw, const float* __restrict__ ipb,
                        const float* __restrict__ opw, const float* __restrict__ opb,
                        const float* __restrict__ Wkp, const float* __restrict__ Wvp,
                        const float* __restrict__ bkp, const float* __restrict__ bvp,
                        float* __restrict__ WuT, float* __restrict__ bu,
                        float* __restrict__ wd, float* __restrict__ ddp,
                        float* __restrict__ Wovt, float* __restrict__ bov) {
  int bid = blockIdx.x, tid = threadIdx.x;
  if (bid < 320) {
    int e = bid;
    float acc = 0.f;
    for (int o = 0; o < E_; ++o) acc += Wkp[(size_t)o * H_ + tid] * ipw[(size_t)o * E_ + e];
    WuT[(size_t)e * H_ + tid] = acc;
  } else if (bid < 576) {
    int jj = bid - 320;
    for (int i = tid; i < E_; i += 256) {
      float acc = 0.f;
      for (int o = 0; o < E_; ++o) acc += opw[(size_t)i * E_ + o] * Wvp[(size_t)o * H_ + jj];
      Wovt[(size_t)jj * E_ + i] = acc;
    }
  } else {
    {
      float acc = 0.f;
      for (int o = 0; o < E_; ++o) acc += Wkp[(size_t)o * H_ + tid] * ipb[o];
      bu[tid] = acc;
    }
    for (int idx = tid; idx < E_; idx += 256) {
      float a1 = 0.f, a2 = opb[idx];
      for (int o = 0; o < E_; ++o) {
        a1 += ipw[(size_t)o * E_ + idx] * bkp[o];
        a2 += opw[(size_t)idx * E_ + o] * bvp[o];
      }
      wd[idx] = a1; bov[idx] = a2;
    }
    if (tid == 0) {
      float acc = 0.f;
      for (int o = 0; o < E_; ++o) acc += ipb[o] * bkp[o];
      ddp[0] = acc;
    }
  }
}

// ---------------------------------------------------------------------------
// LSTM persistent kernel. 256 blocks = 8 batch-groups(64 rows) x 32 n-slices
// (8 h-cols each; gate rows {hc,256+hc,512+hc,768+hc} so the nonlinearity is
// block-local). Weights live in LDS; per-step group barrier (32 blocks) via
// monotonic device-scope counters. gates = [x_t|h_{t-1}] @ Wg^T via
// mfma_f32_16x16x32_bf16; c-state in fp32 registers.
// ---------------------------------------------------------------------------
struct LstmArgs {
  const u16* xbf; u16* hs; const u16* Wg; const float* bb; u32* cnt;
};

__launch_bounds__(256, 1)
__global__ void k_lstm(LstmArgs A) {
  const int g   = blockIdx.x & 7;
  const int n   = blockIdx.x >> 3;            // 0..31
  const int tid = threadIdx.x;
  const int wid = tid >> 6, lane = tid & 63;
  __shared__ __align__(16) u16 Wl[32 * 392];  // 32 gate rows x 384 K, pad to 392

  for (int idx = tid; idx < 32 * 48; idx += 256) {
    int ln = idx / 48, c8 = idx % 48;
    int gr = (ln >> 3) * 256 + n * 8 + (ln & 7);
    *(uint4*)&Wl[ln * 392 + c8 * 8] = *(const uint4*)&A.Wg[(size_t)gr * 384 + c8 * 8];
  }
  const int j  = lane & 7;
  const int gc = n * 8 + j;
  const float bbi = A.bb[gc], bbf2 = A.bb[256 + gc];
  const float bbg = A.bb[512 + gc], bbo = A.bb[768 + gc];
  __syncthreads();

  const int quad = lane >> 4;
  const int mrow = lane & 15;                 // A-row (m) and B-col (n) index
  const int brow = g * 64 + wid * 16 + mrow;  // batch row for A frags
  const int erow0 = g * 64 + wid * 16 + quad * 4;  // epilogue rows base
  const bool hi = (lane & 8) != 0;
  float crs[4] = {0.f, 0.f, 0.f, 0.f};
  u32* mycnt = A.cnt + g * 64;
  u32 target = 0;

  for (int t = 0; t < T_; ++t) {
    f32x4 acc0 = {0.f, 0.f, 0.f, 0.f}, acc1 = {0.f, 0.f, 0.f, 0.f};
    const u16* xrow = A.xbf + ((size_t)t * B_ + brow) * DIN + quad * 8;
    const u16* hrow = A.hs + ((size_t)t * B_ + brow) * H_ + quad * 8;
#pragma unroll
    for (int kc = 0; kc < 12; ++kc) {
      const int koff = kc * 32;
      uint4 araw = (kc < 4) ? *(const uint4*)(xrow + koff)
                            : *(const uint4*)(hrow + (koff - 128));
      short8 av = __builtin_bit_cast(short8, araw);
      short8 bv0 = __builtin_bit_cast(short8, *(const uint4*)&Wl[mrow * 392 + koff + quad * 8]);
      short8 bv1 = __builtin_bit_cast(short8, *(const uint4*)&Wl[(16 + mrow) * 392 + koff + quad * 8]);
      acc0 = __builtin_amdgcn_mfma_f32_16x16x32_bf16(av, bv0, acc0, 0, 0, 0);
      acc1 = __builtin_amdgcn_mfma_f32_16x16x32_bf16(av, bv1, acc1, 0, 0, 0);
    }
    // epilogue: lanes bit3=0 hold i (tile0) & g (tile1); bit3=1 hold f & o
    u16* hout = A.hs + (size_t)(t + 1) * B_ * H_;
#pragma unroll
    for (int r = 0; r < 4; ++r) {
      float x0 = acc0[r], x1v = acc1[r];
      float y0 = __shfl_xor(x0, 8, 64);
      float y1 = __shfl_xor(x1v, 8, 64);
      float iv = (hi ? y0 : x0) + bbi;
      float fv = (hi ? x0 : y0) + bbf2;
      float gv = (hi ? y1 : x1v) + bbg;
      float ov = (hi ? x1v : y1) + bbo;
      float cc = sigf(fv) * crs[r] + sigf(iv) * tanhfast(gv);
      crs[r] = cc;
      float hh = sigf(ov) * tanhfast(cc);
      if (!hi) hout[(size_t)(erow0 + r) * H_ + gc] = f2b(hh);
    }
    // ---- group barrier (release h_t, acquire peers' h_t) ----
    target += 32;
    if (t != T_ - 1) {
      __syncthreads();
      if (tid == 0) {
        __threadfence();
        atomicAdd(mycnt, 1u);
        int guard = 0;
        while (__hip_atomic_load(mycnt, __ATOMIC_RELAXED, __HIP_MEMORY_SCOPE_AGENT) < target) {
          __builtin_amdgcn_s_sleep(1);
          if (++guard > (1 << 22)) break;
        }
        __threadfence();
      }
      __syncthreads();
    }
  }
}

// ---------------------------------------------------------------------------
// k_u: u_b = WuT^T-style matvec on z=[h_T, s];  d_b = wd.z + dd
// ---------------------------------------------------------------------------
__global__ void k_u(const u16* __restrict__ hs, const float* __restrict__ s,
                    const float* __restrict__ WuT, const float* __restrict__ bu,
                    const float* __restrict__ wd, const float* __restrict__ ddp,
                    float* __restrict__ u, float* __restrict__ dvec) {
  int b = blockIdx.x, tid = threadIdx.x;
  __shared__ float z[E_];
  __shared__ float red[256];
  z[tid] = b2f(hs[((size_t)T_ * B_ + b) * H_ + tid]);
  if (tid < F_) z[H_ + tid] = s[(size_t)b * F_ + tid];
  __syncthreads();
  float acc = bu[tid];
  for (int e = 0; e < E_; ++e) acc += WuT[(size_t)e * H_ + tid] * z[e];
  u[(size_t)b * H_ + tid] = acc;
  float p = 0.f;
  for (int e = tid; e < E_; e += 256) p += wd[e] * z[e];
  red[tid] = p;
  __syncthreads();
  for (int s2 = 128; s2 > 0; s2 >>= 1) {
    if (tid < s2) red[tid] += red[tid + s2];
    __syncthreads();
  }
  if (tid == 0) dvec[b] = red[0] + ddp[0];
}

// ---------------------------------------------------------------------------
// k_aw: scores -> softmax -> w_b = sum_t attn_t * h_t   (block per batch row)
// ---------------------------------------------------------------------------
__global__ void k_aw(const u16* __restrict__ hs, const float* __restrict__ u,
                     const float* __restrict__ dvec, float* __restrict__ wv) {
  int b = blockIdx.x, tid = threadIdx.x;
  int wid = tid >> 6, lane = tid & 63;
  __shared__ float sc[T_];
  __shared__ float red[256];
  const float db = dvec[b];
  const float scale = 0.055901699437494745f;  // 1/sqrt(320)
  float4 ul = *(const float4*)&u[(size_t)b * H_ + lane * 4];
  for (int tt = 0; tt < 64; ++tt) {
    int t = wid * 64 + tt;
    u32 rw0 = ((const u32*)(hs + ((size_t)(t + 1) * B_ + b) * H_))[lane * 2];
    u32 rw1 = ((const u32*)(hs + ((size_t)(t + 1) * B_ + b) * H_))[lane * 2 + 1];
    union { u32 uu; float f; } f0, f1, f2, f3;
    f0.uu = rw0 << 16; f1.uu = rw0 & 0xFFFF0000u;
    f2.uu = rw1 << 16; f3.uu = rw1 & 0xFFFF0000u;
    float p = f0.f * ul.x + f1.f * ul.y + f2.f * ul.z + f3.f * ul.w;
#pragma unroll
    for (int off = 32; off > 0; off >>= 1) p += __shfl_xor(p, off, 64);
    if (lane == 0) sc[t] = (p + db) * scale;
  }
  __syncthreads();
  float v = sc[tid];
  red[tid] = v;
  __syncthreads();
  for (int s2 = 128; s2 > 0; s2 >>= 1) {
    if (tid < s2) red[tid] = fmaxf(red[tid], red[tid + s2]);
    __syncthreads();
  }
  float m = red[0];
  __syncthreads();
  float e = __expf(v - m);
  red[tid] = e;
  __syncthreads();
  for (int s2 = 128; s2 > 0; s2 >>= 1) {
    if (tid < s2) red[tid] += red[tid + s2];
    __syncthreads();
  }
  float inv = 1.f / red[0];
  __syncthreads();
  sc[tid] = e * inv;
  __syncthreads();
  float acc = 0.f;
#pragma unroll 8
  for (int t = 0; t < T_; ++t) {
    acc += sc[t] * b2f(hs[((size_t)(t + 1) * B_ + b) * H_ + tid]);
  }
  wv[(size_t)b * H_ + tid] = acc;
}

// ---------------------------------------------------------------------------
// k_ao: merged_state = [Wov @ w_b + bov, s_b]
// ---------------------------------------------------------------------------
__global__ void k_ao(const float* __restrict__ wv, const float* __restrict__ Wovt,
                     const float* __restrict__ bov, const float* __restrict__ s,
                     float* __restrict__ mst) {
  int b = blockIdx.x, tid = threadIdx.x;
  __shared__ float wl[H_];
  if (tid < H_) wl[tid] = wv[(size_t)b * H_ + tid];
  __syncthreads();
  if (tid < E_) {
    float acc = bov[tid];
    for (int jj = 0; jj < H_; ++jj) acc += Wovt[(size_t)jj * E_ + tid] * wl[jj];
    mst[(size_t)b * DM + tid] = acc;
  } else if (tid < DM) {
    mst[(size_t)b * DM + tid] = s[(size_t)b * F_ + (tid - E_)];
  }
}

// ---------------------------------------------------------------------------
// k_vqc: 10-qubit statevector sim; 1 combined gate per (layer,qubit); psi in LDS
// ---------------------------------------------------------------------------
__global__ void k_vqc(const float* __restrict__ mst, const float* __restrict__ uwg,
                      float* __restrict__ qf) {
  int b = blockIdx.x, tid = threadIdx.x;
  __shared__ float2 psi[1024];
  __shared__ float ang[40];
  __shared__ float uwl[320];
  __shared__ float part[4][10];
  if (tid < 40) ang[tid] = tanhf(mst[(size_t)b * DM + tid]) * PI_F;
  uwl[tid] = uwg[tid];
  if (tid < 64) uwl[256 + tid] = uwg[256 + tid];
#pragma unroll
  for (int k = 0; k < 4; ++k) psi[tid + k * 256] = make_float2(0.03125f, 0.f);
  __syncthreads();
  for (int l = 0; l < 4; ++l) {
    for (int q = 0; q < 10; ++q) {
      int lq = l * 10 + q;
      float a = ang[lq];
      float ca = __cosf(0.5f * a), sa = __sinf(0.5f * a);
      float cs = ca * sa;
      float2 m00 = make_float2(ca * ca, sa * sa);
      float2 m01 = make_float2(-cs, -cs);
      float2 m10 = make_float2(cs, -cs);
      float2 m11 = make_float2(ca * ca, -sa * sa);
      const float* uwp = &uwl[lq * 8];
      float2 a00 = make_float2(uwp[0], uwp[1]), a01 = make_float2(uwp[2], uwp[3]);
      float2 a10 = make_float2(uwp[4], uwp[5]), a11 = make_float2(uwp[6], uwp[7]);
      float2 u00 = cadd(cmul(a00, m00), cmul(a01, m10));
      float2 u01 = cadd(cmul(a00, m01), cmul(a01, m11));
      float2 u10 = cadd(cmul(a10, m00), cmul(a11, m10));
      float2 u11 = cadd(cmul(a10, m01), cmul(a11, m11));
      int bp = 9 - q;
      __syncthreads();
#pragma unroll
      for (int k = 0; k < 2; ++k) {
        int p = tid + k * 256;
        int i0 = ((p >> bp) << (bp + 1)) | (p & ((1 << bp) - 1));
        int i1 = i0 | (1 << bp);
        float2 A0 = psi[i0], A1 = psi[i1];
        psi[i0] = cadd(cmul(u00, A0), cmul(u01, A1));
        psi[i1] = cadd(cmul(u10, A0), cmul(u11, A1));
      }
    }
    for (int q = 0; q < 9; ++q) {  // CNOT(q, q+1): adjacent bits
      int lo = 8 - q;
      __syncthreads();
      int p = tid;
      int i0 = ((p >> lo) << (lo + 2)) | (2 << lo) | (p & ((1 << lo) - 1));
      int i1 = i0 | (1 << lo);
      float2 tmp = psi[i0]; psi[i0] = psi[i1]; psi[i1] = tmp;
    }
    __syncthreads();  // CNOT(9, 0): ctrl bit0, tgt bit9
    {
      int i0 = (tid << 1) | 1;
      int i1 = i0 | 512;
      float2 tmp = psi[i0]; psi[i0] = psi[i1]; psi[i1] = tmp;
    }
  }
  __syncthreads();
  float acc[10];
#pragma unroll
  for (int q = 0; q < 10; ++q) acc[q] = 0.f;
#pragma unroll
  for (int k = 0; k < 4; ++k) {
    int idx = tid + k * 256;
    float2 A = psi[idx];
    float pr = A.x * A.x + A.y * A.y;
#pragma unroll
    for (int q = 0; q < 10; ++q) acc[q] += ((idx >> (9 - q)) & 1) ? -pr : pr;
  }
  int lane = tid & 63, wid = tid >> 6;
#pragma unroll
  for (int q = 0; q < 10; ++q) {
    float vq = acc[q];
#pragma unroll
    for (int off = 32; off > 0; off >>= 1) vq += __shfl_xor(vq, off, 64);
    if (lane == 0) part[wid][q] = vq;
  }
  __syncthreads();
  if (tid < 10) qf[(size_t)b * 10 + tid] = part[0][tid] + part[1][tid] + part[2][tid] + part[3][tid];
}

// ---------------------------------------------------------------------------
// k_mlp: x1 = relu([mst,qf] @ W1^T + b1); out = x1 @ W2^T + b2
// ---------------------------------------------------------------------------
__global__ void k_mlp(const float* __restrict__ mst, const float* __restrict__ qf,
                      const float* __restrict__ W1t, const float* __restrict__ b1,
                      const float* __restrict__ W2, const float* __restrict__ b2,
                      float* __restrict__ out) {
  int b = blockIdx.x, tid = threadIdx.x;
  __shared__ float mg[KMLP];
  __shared__ float x1[NL1];
  __shared__ float red[256];
  for (int i = tid; i < DM; i += 256) mg[i] = mst[(size_t)b * DM + i];
  if (tid < 10) mg[DM + tid] = qf[(size_t)b * 10 + tid];
  __syncthreads();
#pragma unroll
  for (int hh = 0; hh < 2; ++hh) {
    int nn = tid + hh * 256;
    float acc = b1[nn];
#pragma unroll 4
    for (int k = 0; k < KMLP; ++k) acc += W1t[(size_t)k * NL1 + nn] * mg[k];
    x1[nn] = fmaxf(acc, 0.f);
  }
  __syncthreads();
  int a = tid >> 5, l32 = tid & 31;
  float p = 0.f;
  for (int k = l32; k < NL1; k += 32) p += x1[k] * W2[(size_t)a * NL1 + k];
  red[tid] = p;
  __syncthreads();
  if (tid < 8) {
    float acc = b2[tid];
#pragma unroll
    for (int i = 0; i < 32; ++i) acc += red[tid * 32 + i];
    out[(size_t)b * NACT + tid] = acc;
  }
}

// ---------------------------------------------------------------------------
extern "C" void kernel_launch(void* const* d_in, const int* in_sizes, int n_in,
                              void* d_out, int out_size, void* d_ws, size_t ws_size,
                              hipStream_t stream) {
  const float* s      = (const float*)d_in[0];
  const float* lstm_s = (const float*)d_in[1];
  const float* W_ih   = (const float*)d_in[2];
  const float* W_hh   = (const float*)d_in[3];
  const float* b_ih   = (const float*)d_in[4];
  const float* b_hh   = (const float*)d_in[5];
  const float* projW  = (const float*)d_in[6];
  const float* projb  = (const float*)d_in[7];
  const float* ipw    = (const float*)d_in[8];
  const float* ipb    = (const float*)d_in[9];
  const float* opw    = (const float*)d_in[10];
  const float* opb    = (const float*)d_in[11];
  const float* qw     = (const float*)d_in[12];
  const float* W1     = (const float*)d_in[13];
  const float* b1     = (const float*)d_in[14];
  const float* W2     = (const float*)d_in[15];
  const float* b2     = (const float*)d_in[16];
  float* out = (float*)d_out;

  char* wsb = (char*)d_ws;
  size_t off = 0;
  auto alloc = [&](size_t bytes) -> void* {
    void* p = wsb + off;
    off = (off + bytes + 255) & ~(size_t)255;
    return p;
  };
  u16*  xbf  = (u16*)alloc((size_t)T_ * B_ * DIN * 2);
  u16*  hs   = (u16*)alloc((size_t)(T_ + 1) * B_ * H_ * 2);
  u16*  Wg   = (u16*)alloc((size_t)G4 * 384 * 2);
  float* bb  = (float*)alloc(G4 * 4);
  float* Wkp = (float*)alloc((size_t)E_ * H_ * 4);
  float* Wvp = (float*)alloc((size_t)E_ * H_ * 4);
  float* bkp = (float*)alloc(E_ * 4);
  float* bvp = (float*)alloc(E_ * 4);
  float* WuT = (float*)alloc((size_t)E_ * H_ * 4);
  float* bu  = (float*)alloc(H_ * 4);
  float* wd  = (float*)alloc(E_ * 4);
  float* ddp = (float*)alloc(256);
  float* Wovt= (float*)alloc((size_t)H_ * E_ * 4);
  float* bov = (float*)alloc(E_ * 4);
  float* uu  = (float*)alloc((size_t)B_ * H_ * 4);
  float* dvec= (float*)alloc(B_ * 4);
  float* wv  = (float*)alloc((size_t)B_ * H_ * 4);
  float* mst = (float*)alloc((size_t)B_ * DM * 4);
  float* qf  = (float*)alloc((size_t)B_ * 10 * 4);
  float* uw  = (float*)alloc(40 * 8 * 4);
  float* W1t = (float*)alloc((size_t)KMLP * NL1 * 4);
  u32*  cnt  = (u32*)alloc(512 * 4);
  (void)ws_size; (void)in_sizes; (void)n_in; (void)out_size;

  hipLaunchKernelGGL(k_prep1, dim3(9241), dim3(256), 0, stream,
                     lstm_s, W_ih, W_hh, b_ih, b_hh, ipw, ipb, projb, qw, W1,
                     xbf, hs, Wg, bb, W1t, uw, bkp, bvp, cnt);
  hipLaunchKernelGGL(k_prep2, dim3(640), dim3(256), 0, stream, ipw, projW, Wkp, Wvp);
  hipLaunchKernelGGL(k_prep3, dim3(577), dim3(256), 0, stream,
                     ipw, ipb, opw, opb, Wkp, Wvp, bkp, bvp, WuT, bu, wd, ddp, Wovt, bov);

  LstmArgs la;
  la.xbf = xbf; la.hs = hs; la.Wg = Wg; la.bb = bb; la.cnt = cnt;
  void* kargs[] = { (void*)&la };
  hipError_t ce = hipLaunchCooperativeKernel(reinterpret_cast<const void*>(&k_lstm),
                                             dim3(256), dim3(256), kargs, 0, stream);
  if (ce != hipSuccess) {
    // fallback: plain launch (256 blocks on 256 CUs co-schedule in practice)
    hipLaunchKernelGGL(k_lstm, dim3(256), dim3(256), 0, stream, la);
  }

  hipLaunchKernelGGL(k_u,   dim3(512), dim3(256), 0, stream, hs, s, WuT, bu, wd, ddp, uu, dvec);
  hipLaunchKernelGGL(k_aw,  dim3(512), dim3(256), 0, stream, hs, uu, dvec, wv);
  hipLaunchKernelGGL(k_ao,  dim3(512), dim3(384), 0, stream, wv, Wovt, bov, s, mst);
  hipLaunchKernelGGL(k_vqc, dim3(512), dim3(256), 0, stream, mst, uw, qf);
  hipLaunchKernelGGL(k_mlp, dim3(512), dim3(256), 0, stream, mst, qf, W1t, b1, W2, b2, out);
}

// Round 2
// 1738.607 us; speedup vs baseline: 2.0804x; 2.0804x over previous
//
#include <hip/hip_runtime.h>
#include <hip/hip_bf16.h>
#include <math.h>

typedef unsigned int u32;
typedef unsigned long long u64;
typedef unsigned short u16;
typedef __attribute__((ext_vector_type(8))) short short8;
typedef __attribute__((ext_vector_type(4))) float f32x4;

#define PI_F 3.14159265358979f
#define B_   512
#define T_   256
#define DIN  128
#define H_   256
#define G4   1024
#define F_   64
#define E_   320
#define DM   384
#define NL1  512
#define NACT 8
#define KMLP 394

__device__ __forceinline__ float b2f(u16 h) {
  union { u32 u; float f; } v; v.u = ((u32)h) << 16; return v.f;
}
__device__ __forceinline__ u16 f2b(float f) {
  union { float f; u32 u; } v; v.f = f;
  u32 r = (v.u + 0x7FFFu + ((v.u >> 16) & 1u)) >> 16;
  return (u16)r;
}
__device__ __forceinline__ float sigf(float x) { return 1.0f / (1.0f + __expf(-x)); }
__device__ __forceinline__ float tanhfast(float x) { return 2.0f / (1.0f + __expf(-2.0f * x)) - 1.0f; }
__device__ __forceinline__ float2 cmul(float2 a, float2 b) {
  return make_float2(a.x * b.x - a.y * b.y, a.x * b.y + a.y * b.x);
}
__device__ __forceinline__ float2 cadd(float2 a, float2 b) {
  return make_float2(a.x + b.x, a.y + b.y);
}
// Fine-grained cross-XCD coherent access (bypasses non-coherent L1/L2; no
// cache-maintenance ops, unlike __threadfence which wb/invalidates L2 on gfx950)
__device__ __forceinline__ u64 ld_agent_u64(const u16* p) {
  return __hip_atomic_load((const u64*)p, __ATOMIC_RELAXED, __HIP_MEMORY_SCOPE_AGENT);
}
__device__ __forceinline__ void st_agent_u32(u32* p, u32 v) {
  __hip_atomic_store(p, v, __ATOMIC_RELAXED, __HIP_MEMORY_SCOPE_AGENT);
}

// ---------------------------------------------------------------------------
// prep1: x transpose+bf16, Wg=[W_ih|W_hh] bf16, zero hs[0], W1t, bb, uw, bkp,
// bvp, zero barrier counters
// ---------------------------------------------------------------------------
__global__ void k_prep1(const float* __restrict__ lstm_s,
                        const float* __restrict__ W_ih,
                        const float* __restrict__ W_hh,
                        const float* __restrict__ b_ih,
                        const float* __restrict__ b_hh,
                        const float* __restrict__ ipw,
                        const float* __restrict__ ipb,
                        const float* __restrict__ projb,
                        const float* __restrict__ qw,
                        const float* __restrict__ W1,
                        u16* __restrict__ xbf,
                        u16* __restrict__ hs,
                        u16* __restrict__ Wg,
                        float* __restrict__ bb,
                        float* __restrict__ W1t,
                        float* __restrict__ uw,
                        float* __restrict__ bkp,
                        float* __restrict__ bvp,
                        u32* __restrict__ cnt) {
  const int bid = blockIdx.x;
  const int tid = threadIdx.x;
  if (bid < 8192) {                       // lstm_s (B,T,128) -> xbf (T,B,128) bf16
    u32 u = (u32)bid * 256u + tid;        // < 2097152 uint4 units
    u32 c8 = u & 15u, b = (u >> 4) & 511u, t = u >> 13;
    const float* src = lstm_s + ((size_t)b * T_ + t) * DIN + c8 * 8;
    union { u16 h[8]; uint4 v; } tmp;
#pragma unroll
    for (int i = 0; i < 8; ++i) tmp.h[i] = f2b(src[i]);
    *(uint4*)(xbf + ((size_t)t * B_ + b) * DIN + c8 * 8) = tmp.v;
  } else if (bid < 8384) {                // Wg (1024 x 384) bf16
    u32 u = (u32)(bid - 8192) * 256u + tid;  // < 49152
    u32 c8 = u % 48u, r = u / 48u;
    const float* src = (c8 < 16) ? (W_ih + (size_t)r * DIN + c8 * 8)
                                 : (W_hh + (size_t)r * H_ + (c8 - 16) * 8);
    union { u16 h[8]; uint4 v; } tmp;
#pragma unroll
    for (int i = 0; i < 8; ++i) tmp.h[i] = f2b(src[i]);
    *(uint4*)(Wg + (size_t)r * 384 + c8 * 8) = tmp.v;
  } else if (bid < 8448) {                // zero hs[0]
    u32 u = (u32)(bid - 8384) * 256u + tid;  // < 16384
    ((uint4*)hs)[u] = make_uint4(0, 0, 0, 0);
  } else if (bid < 9236) {                // W1t[k][n] = W1[n][k]
    u32 u = (u32)(bid - 8448) * 256u + tid;  // < 201728
    u32 k = u / 512u, nn = u % 512u;
    W1t[u] = W1[(size_t)nn * KMLP + k];
  } else if (bid == 9236) {               // bb, cnt, uw
    for (int i = tid; i < 1024; i += 256) bb[i] = b_ih[i] + b_hh[i];
    for (int i = tid; i < 512; i += 256) cnt[i] = 0u;
    if (tid < 40) {
      float w0 = qw[tid * 3 + 0], w1 = qw[tid * 3 + 1], w2 = qw[tid * 3 + 2];
      float c0 = cosf(0.5f * w0), s0 = sinf(0.5f * w0);
      float c1 = cosf(0.5f * w1), s1 = sinf(0.5f * w1);
      float c2 = cosf(0.5f * w2), s2 = sinf(0.5f * w2);
      float2 e0m = make_float2(c0, -s0), e0p = make_float2(c0, s0);
      float2 e2m = make_float2(c2, -s2), e2p = make_float2(c2, s2);
      // T1 = RY(w1) @ RZ(w0)
      float2 t00 = make_float2(c1 * e0m.x, c1 * e0m.y);
      float2 t01 = make_float2(-s1 * e0p.x, -s1 * e0p.y);
      float2 t10 = make_float2(s1 * e0m.x, s1 * e0m.y);
      float2 t11 = make_float2(c1 * e0p.x, c1 * e0p.y);
      // U = RZ(w2) @ T1
      float2 u00 = cmul(e2m, t00), u01 = cmul(e2m, t01);
      float2 u10 = cmul(e2p, t10), u11 = cmul(e2p, t11);
      float* o = uw + tid * 8;
      o[0] = u00.x; o[1] = u00.y; o[2] = u01.x; o[3] = u01.y;
      o[4] = u10.x; o[5] = u10.y; o[6] = u11.x; o[7] = u11.y;
    }
  } else if (bid <= 9238) {               // bkp = Wk @ proj_b + bk
    int o = (bid - 9237) * 256 + tid;
    if (o < E_) {
      float acc = ipb[E_ + o];
      for (int e = 0; e < E_; ++e) acc += ipw[(size_t)(E_ + o) * E_ + e] * projb[e];
      bkp[o] = acc;
    }
  } else {                                // bvp = Wv @ proj_b + bv
    int o = (bid - 9239) * 256 + tid;
    if (o < E_) {
      float acc = ipb[2 * E_ + o];
      for (int e = 0; e < E_; ++e) acc += ipw[(size_t)(2 * E_ + o) * E_ + e] * projb[e];
      bvp[o] = acc;
    }
  }
}

// ---------------------------------------------------------------------------
// prep2: Wk' = Wk @ proj_W, Wv' = Wv @ proj_W  (each 320x256)
// ---------------------------------------------------------------------------
__global__ void k_prep2(const float* __restrict__ ipw, const float* __restrict__ projW,
                        float* __restrict__ Wkp, float* __restrict__ Wvp) {
  int bid = blockIdx.x, tid = threadIdx.x;
  int o = (bid < 320) ? bid : (bid - 320);
  const float* wrow = ipw + (size_t)((bid < 320 ? E_ : 2 * E_) + o) * E_;
  float acc = 0.f;
  for (int e = 0; e < E_; ++e) acc += wrow[e] * projW[(size_t)e * H_ + tid];
  (bid < 320 ? Wkp : Wvp)[(size_t)o * H_ + tid] = acc;
}

// ---------------------------------------------------------------------------
// prep3: WuT[e][j] = sum_o Wkp[o][j]*Wq[o][e];  Wovt[j][i] = sum_o Wo[i][o]*Wvp[o][j]
// plus bu, wd, dd, bov
// ---------------------------------------------------------------------------
__global__ void k_prep3(const float* __restrict__ ipw, const float* __restrict__ ipb,
                        const float* __restrict__ opw, const float* __restrict__ opb,
                        const float* __restrict__ Wkp, const float* __restrict__ Wvp,
                        const float* __restrict__ bkp, const float* __restrict__ bvp,
                        float* __restrict__ WuT, float* __restrict__ bu,
                        float* __restrict__ wd, float* __restrict__ ddp,
                        float* __restrict__ Wovt, float* __restrict__ bov) {
  int bid = blockIdx.x, tid = threadIdx.x;
  if (bid < 320) {
    int e = bid;
    float acc = 0.f;
    for (int o = 0; o < E_; ++o) acc += Wkp[(size_t)o * H_ + tid] * ipw[(size_t)o * E_ + e];
    WuT[(size_t)e * H_ + tid] = acc;
  } else if (bid < 576) {
    int jj = bid - 320;
    for (int i = tid; i < E_; i += 256) {
      float acc = 0.f;
      for (int o = 0; o < E_; ++o) acc += opw[(size_t)i * E_ + o] * Wvp[(size_t)o * H_ + jj];
      Wovt[(size_t)jj * E_ + i] = acc;
    }
  } else {
    {
      float acc = 0.f;
      for (int o = 0; o < E_; ++o) acc += Wkp[(size_t)o * H_ + tid] * ipb[o];
      bu[tid] = acc;
    }
    for (int idx = tid; idx < E_; idx += 256) {
      float a1 = 0.f, a2 = opb[idx];
      for (int o = 0; o < E_; ++o) {
        a1 += ipw[(size_t)o * E_ + idx] * bkp[o];
        a2 += opw[(size_t)idx * E_ + o] * bvp[o];
      }
      wd[idx] = a1; bov[idx] = a2;
    }
    if (tid == 0) {
      float acc = 0.f;
      for (int o = 0; o < E_; ++o) acc += ipb[o] * bkp[o];
      ddp[0] = acc;
    }
  }
}

// ---------------------------------------------------------------------------
// LSTM persistent kernel. 256 blocks = 8 batch-groups(64 rows) x 32 n-slices.
// Cross-XCD h handoff via fine-grained AGENT-scope atomics (write-through /
// cache-bypass) — NO fences, so no per-step L2 writeback/invalidate (the R1
// 12.4us/step stall). Barrier = vmcnt(0) drain + relaxed agent counter.
// ---------------------------------------------------------------------------
struct LstmArgs {
  const u16* xbf; u16* hs; const u16* Wg; const float* bb; u32* cnt;
};

__launch_bounds__(256, 1)
__global__ void k_lstm(LstmArgs A) {
  const int g   = blockIdx.x & 7;
  const int n   = blockIdx.x >> 3;            // 0..31
  const int tid = threadIdx.x;
  const int wid = tid >> 6, lane = tid & 63;
  __shared__ __align__(16) u16 Wl[32 * 392];  // 32 gate rows x 384 K, pad to 392

  for (int idx = tid; idx < 32 * 48; idx += 256) {
    int ln = idx / 48, c8 = idx % 48;
    int gr = (ln >> 3) * 256 + n * 8 + (ln & 7);
    *(uint4*)&Wl[ln * 392 + c8 * 8] = *(const uint4*)&A.Wg[(size_t)gr * 384 + c8 * 8];
  }
  const int j  = lane & 7;
  const int gc = n * 8 + j;
  const float bbi = A.bb[gc], bbf2 = A.bb[256 + gc];
  const float bbg = A.bb[512 + gc], bbo = A.bb[768 + gc];
  __syncthreads();

  const int quad = lane >> 4;
  const int mrow = lane & 15;                 // A-row (m) and B-col (n) index
  const int brow = g * 64 + wid * 16 + mrow;  // batch row for A frags
  const int erow0 = g * 64 + wid * 16 + quad * 4;  // epilogue rows base
  const bool hi = (lane & 8) != 0;
  float crs[4] = {0.f, 0.f, 0.f, 0.f};
  u32* mycnt = A.cnt + g * 64;
  u32 target = 0;

  for (int t = 0; t < T_; ++t) {
    f32x4 acc0 = {0.f, 0.f, 0.f, 0.f}, acc1 = {0.f, 0.f, 0.f, 0.f};
    const u16* xrow = A.xbf + ((size_t)t * B_ + brow) * DIN + quad * 8;
    const u16* hrow = A.hs + ((size_t)t * B_ + brow) * H_ + quad * 8;
#pragma unroll
    for (int kc = 0; kc < 12; ++kc) {
      const int koff = kc * 32;
      uint4 araw;
      if (kc < 4) {
        araw = *(const uint4*)(xrow + koff);
      } else {
        // h from other XCDs: coherent (cache-bypass) loads
        u64 lo = ld_agent_u64(hrow + (koff - 128));
        u64 hi2 = ld_agent_u64(hrow + (koff - 128) + 4);
        araw = make_uint4((u32)lo, (u32)(lo >> 32), (u32)hi2, (u32)(hi2 >> 32));
      }
      short8 av = __builtin_bit_cast(short8, araw);
      short8 bv0 = __builtin_bit_cast(short8, *(const uint4*)&Wl[mrow * 392 + koff + quad * 8]);
      short8 bv1 = __builtin_bit_cast(short8, *(const uint4*)&Wl[(16 + mrow) * 392 + koff + quad * 8]);
      acc0 = __builtin_amdgcn_mfma_f32_16x16x32_bf16(av, bv0, acc0, 0, 0, 0);
      acc1 = __builtin_amdgcn_mfma_f32_16x16x32_bf16(av, bv1, acc1, 0, 0, 0);
    }
    // epilogue: lanes bit3=0 hold i (tile0) & g (tile1); bit3=1 hold f & o
    u16* hout = A.hs + (size_t)(t + 1) * B_ * H_;
#pragma unroll
    for (int r = 0; r < 4; ++r) {
      float x0 = acc0[r], x1v = acc1[r];
      float y0 = __shfl_xor(x0, 8, 64);
      float y1 = __shfl_xor(x1v, 8, 64);
      float iv = (hi ? y0 : x0) + bbi;
      float fv = (hi ? x0 : y0) + bbf2;
      float gv = (hi ? y1 : x1v) + bbg;
      float ov = (hi ? x1v : y1) + bbo;
      float cc = sigf(fv) * crs[r] + sigf(iv) * tanhfast(gv);
      crs[r] = cc;
      float hh = sigf(ov) * tanhfast(cc);
      float hh2 = __shfl_xor(hh, 1, 64);      // partner column's h
      if (!hi && ((j & 1) == 0)) {
        u32 pk = (u32)f2b(hh) | ((u32)f2b(hh2) << 16);
        st_agent_u32((u32*)(hout + (size_t)(erow0 + r) * H_ + gc), pk);
      }
    }
    // ---- group barrier (release h_t, acquire peers' h_t) — fence-free ----
    target += 32;
    if (t != T_ - 1) {
      asm volatile("s_waitcnt vmcnt(0)" ::: "memory");  // own h stores at IF$
      __syncthreads();                                   // all waves drained
      if (tid == 0) {
        __hip_atomic_fetch_add(mycnt, 1u, __ATOMIC_RELAXED, __HIP_MEMORY_SCOPE_AGENT);
        int guard = 0;
        while (__hip_atomic_load(mycnt, __ATOMIC_RELAXED, __HIP_MEMORY_SCOPE_AGENT) < target) {
          __builtin_amdgcn_s_sleep(1);
          if (++guard > (1 << 24)) break;
        }
      }
      __syncthreads();
    }
  }
}

// ---------------------------------------------------------------------------
// k_u: u_b = WuT^T-style matvec on z=[h_T, s];  d_b = wd.z + dd
// ---------------------------------------------------------------------------
__global__ void k_u(const u16* __restrict__ hs, const float* __restrict__ s,
                    const float* __restrict__ WuT, const float* __restrict__ bu,
                    const float* __restrict__ wd, const float* __restrict__ ddp,
                    float* __restrict__ u, float* __restrict__ dvec) {
  int b = blockIdx.x, tid = threadIdx.x;
  __shared__ float z[E_];
  __shared__ float red[256];
  z[tid] = b2f(hs[((size_t)T_ * B_ + b) * H_ + tid]);
  if (tid < F_) z[H_ + tid] = s[(size_t)b * F_ + tid];
  __syncthreads();
  float acc = bu[tid];
  for (int e = 0; e < E_; ++e) acc += WuT[(size_t)e * H_ + tid] * z[e];
  u[(size_t)b * H_ + tid] = acc;
  float p = 0.f;
  for (int e = tid; e < E_; e += 256) p += wd[e] * z[e];
  red[tid] = p;
  __syncthreads();
  for (int s2 = 128; s2 > 0; s2 >>= 1) {
    if (tid < s2) red[tid] += red[tid + s2];
    __syncthreads();
  }
  if (tid == 0) dvec[b] = red[0] + ddp[0];
}

// ---------------------------------------------------------------------------
// k_aw: scores -> softmax -> w_b = sum_t attn_t * h_t   (block per batch row)
// ---------------------------------------------------------------------------
__global__ void k_aw(const u16* __restrict__ hs, const float* __restrict__ u,
                     const float* __restrict__ dvec, float* __restrict__ wv) {
  int b = blockIdx.x, tid = threadIdx.x;
  int wid = tid >> 6, lane = tid & 63;
  __shared__ float sc[T_];
  __shared__ float red[256];
  const float db = dvec[b];
  const float scale = 0.055901699437494745f;  // 1/sqrt(320)
  float4 ul = *(const float4*)&u[(size_t)b * H_ + lane * 4];
  for (int tt = 0; tt < 64; ++tt) {
    int t = wid * 64 + tt;
    u32 rw0 = ((const u32*)(hs + ((size_t)(t + 1) * B_ + b) * H_))[lane * 2];
    u32 rw1 = ((const u32*)(hs + ((size_t)(t + 1) * B_ + b) * H_))[lane * 2 + 1];
    union { u32 uu; float f; } f0, f1, f2, f3;
    f0.uu = rw0 << 16; f1.uu = rw0 & 0xFFFF0000u;
    f2.uu = rw1 << 16; f3.uu = rw1 & 0xFFFF0000u;
    float p = f0.f * ul.x + f1.f * ul.y + f2.f * ul.z + f3.f * ul.w;
#pragma unroll
    for (int off = 32; off > 0; off >>= 1) p += __shfl_xor(p, off, 64);
    if (lane == 0) sc[t] = (p + db) * scale;
  }
  __syncthreads();
  float v = sc[tid];
  red[tid] = v;
  __syncthreads();
  for (int s2 = 128; s2 > 0; s2 >>= 1) {
    if (tid < s2) red[tid] = fmaxf(red[tid], red[tid + s2]);
    __syncthreads();
  }
  float m = red[0];
  __syncthreads();
  float e = __expf(v - m);
  red[tid] = e;
  __syncthreads();
  for (int s2 = 128; s2 > 0; s2 >>= 1) {
    if (tid < s2) red[tid] += red[tid + s2];
    __syncthreads();
  }
  float inv = 1.f / red[0];
  __syncthreads();
  sc[tid] = e * inv;
  __syncthreads();
  float acc = 0.f;
#pragma unroll 8
  for (int t = 0; t < T_; ++t) {
    acc += sc[t] * b2f(hs[((size_t)(t + 1) * B_ + b) * H_ + tid]);
  }
  wv[(size_t)b * H_ + tid] = acc;
}

// ---------------------------------------------------------------------------
// k_ao: merged_state = [Wov @ w_b + bov, s_b]
// ---------------------------------------------------------------------------
__global__ void k_ao(const float* __restrict__ wv, const float* __restrict__ Wovt,
                     const float* __restrict__ bov, const float* __restrict__ s,
                     float* __restrict__ mst) {
  int b = blockIdx.x, tid = threadIdx.x;
  __shared__ float wl[H_];
  if (tid < H_) wl[tid] = wv[(size_t)b * H_ + tid];
  __syncthreads();
  if (tid < E_) {
    float acc = bov[tid];
    for (int jj = 0; jj < H_; ++jj) acc += Wovt[(size_t)jj * E_ + tid] * wl[jj];
    mst[(size_t)b * DM + tid] = acc;
  } else if (tid < DM) {
    mst[(size_t)b * DM + tid] = s[(size_t)b * F_ + (tid - E_)];
  }
}

// ---------------------------------------------------------------------------
// k_vqc: 10-qubit statevector sim; 1 combined gate per (layer,qubit); psi in LDS
// ---------------------------------------------------------------------------
__global__ void k_vqc(const float* __restrict__ mst, const float* __restrict__ uwg,
                      float* __restrict__ qf) {
  int b = blockIdx.x, tid = threadIdx.x;
  __shared__ float2 psi[1024];
  __shared__ float ang[40];
  __shared__ float uwl[320];
  __shared__ float part[4][10];
  if (tid < 40) ang[tid] = tanhf(mst[(size_t)b * DM + tid]) * PI_F;
  uwl[tid] = uwg[tid];
  if (tid < 64) uwl[256 + tid] = uwg[256 + tid];
#pragma unroll
  for (int k = 0; k < 4; ++k) psi[tid + k * 256] = make_float2(0.03125f, 0.f);
  __syncthreads();
  for (int l = 0; l < 4; ++l) {
    for (int q = 0; q < 10; ++q) {
      int lq = l * 10 + q;
      float a = ang[lq];
      float ca = __cosf(0.5f * a), sa = __sinf(0.5f * a);
      float cs = ca * sa;
      float2 m00 = make_float2(ca * ca, sa * sa);
      float2 m01 = make_float2(-cs, -cs);
      float2 m10 = make_float2(cs, -cs);
      float2 m11 = make_float2(ca * ca, -sa * sa);
      const float* uwp = &uwl[lq * 8];
      float2 a00 = make_float2(uwp[0], uwp[1]), a01 = make_float2(uwp[2], uwp[3]);
      float2 a10 = make_float2(uwp[4], uwp[5]), a11 = make_float2(uwp[6], uwp[7]);
      float2 u00 = cadd(cmul(a00, m00), cmul(a01, m10));
      float2 u01 = cadd(cmul(a00, m01), cmul(a01, m11));
      float2 u10 = cadd(cmul(a10, m00), cmul(a11, m10));
      float2 u11 = cadd(cmul(a10, m01), cmul(a11, m11));
      int bp = 9 - q;
      __syncthreads();
#pragma unroll
      for (int k = 0; k < 2; ++k) {
        int p = tid + k * 256;
        int i0 = ((p >> bp) << (bp + 1)) | (p & ((1 << bp) - 1));
        int i1 = i0 | (1 << bp);
        float2 A0 = psi[i0], A1 = psi[i1];
        psi[i0] = cadd(cmul(u00, A0), cmul(u01, A1));
        psi[i1] = cadd(cmul(u10, A0), cmul(u11, A1));
      }
    }
    for (int q = 0; q < 9; ++q) {  // CNOT(q, q+1): adjacent bits
      int lo = 8 - q;
      __syncthreads();
      int p = tid;
      int i0 = ((p >> lo) << (lo + 2)) | (2 << lo) | (p & ((1 << lo) - 1));
      int i1 = i0 | (1 << lo);
      float2 tmp = psi[i0]; psi[i0] = psi[i1]; psi[i1] = tmp;
    }
    __syncthreads();  // CNOT(9, 0): ctrl bit0, tgt bit9
    {
      int i0 = (tid << 1) | 1;
      int i1 = i0 | 512;
      float2 tmp = psi[i0]; psi[i0] = psi[i1]; psi[i1] = tmp;
    }
  }
  __syncthreads();
  float acc[10];
#pragma unroll
  for (int q = 0; q < 10; ++q) acc[q] = 0.f;
#pragma unroll
  for (int k = 0; k < 4; ++k) {
    int idx = tid + k * 256;
    float2 A = psi[idx];
    float pr = A.x * A.x + A.y * A.y;
#pragma unroll
    for (int q = 0; q < 10; ++q) acc[q] += ((idx >> (9 - q)) & 1) ? -pr : pr;
  }
  int lane = tid & 63, wid = tid >> 6;
#pragma unroll
  for (int q = 0; q < 10; ++q) {
    float vq = acc[q];
#pragma unroll
    for (int off = 32; off > 0; off >>= 1) vq += __shfl_xor(vq, off, 64);
    if (lane == 0) part[wid][q] = vq;
  }
  __syncthreads();
  if (tid < 10) qf[(size_t)b * 10 + tid] = part[0][tid] + part[1][tid] + part[2][tid] + part[3][tid];
}

// ---------------------------------------------------------------------------
// k_mlp: x1 = relu([mst,qf] @ W1^T + b1); out = x1 @ W2^T + b2
// ---------------------------------------------------------------------------
__global__ void k_mlp(const float* __restrict__ mst, const float* __restrict__ qf,
                      const float* __restrict__ W1t, const float* __restrict__ b1,
                      const float* __restrict__ W2, const float* __restrict__ b2,
                      float* __restrict__ out) {
  int b = blockIdx.x, tid = threadIdx.x;
  __shared__ float mg[KMLP];
  __shared__ float x1[NL1];
  __shared__ float red[256];
  for (int i = tid; i < DM; i += 256) mg[i] = mst[(size_t)b * DM + i];
  if (tid < 10) mg[DM + tid] = qf[(size_t)b * 10 + tid];
  __syncthreads();
#pragma unroll
  for (int hh = 0; hh < 2; ++hh) {
    int nn = tid + hh * 256;
    float acc = b1[nn];
#pragma unroll 4
    for (int k = 0; k < KMLP; ++k) acc += W1t[(size_t)k * NL1 + nn] * mg[k];
    x1[nn] = fmaxf(acc, 0.f);
  }
  __syncthreads();
  int a = tid >> 5, l32 = tid & 31;
  float p = 0.f;
  for (int k = l32; k < NL1; k += 32) p += x1[k] * W2[(size_t)a * NL1 + k];
  red[tid] = p;
  __syncthreads();
  if (tid < 8) {
    float acc = b2[tid];
#pragma unroll
    for (int i = 0; i < 32; ++i) acc += red[tid * 32 + i];
    out[(size_t)b * NACT + tid] = acc;
  }
}

// ---------------------------------------------------------------------------
extern "C" void kernel_launch(void* const* d_in, const int* in_sizes, int n_in,
                              void* d_out, int out_size, void* d_ws, size_t ws_size,
                              hipStream_t stream) {
  const float* s      = (const float*)d_in[0];
  const float* lstm_s = (const float*)d_in[1];
  const float* W_ih   = (const float*)d_in[2];
  const float* W_hh   = (const float*)d_in[3];
  const float* b_ih   = (const float*)d_in[4];
  const float* b_hh   = (const float*)d_in[5];
  const float* projW  = (const float*)d_in[6];
  const float* projb  = (const float*)d_in[7];
  const float* ipw    = (const float*)d_in[8];
  const float* ipb    = (const float*)d_in[9];
  const float* opw    = (const float*)d_in[10];
  const float* opb    = (const float*)d_in[11];
  const float* qw     = (const float*)d_in[12];
  const float* W1     = (const float*)d_in[13];
  const float* b1     = (const float*)d_in[14];
  const float* W2     = (const float*)d_in[15];
  const float* b2     = (const float*)d_in[16];
  float* out = (float*)d_out;

  char* wsb = (char*)d_ws;
  size_t off = 0;
  auto alloc = [&](size_t bytes) -> void* {
    void* p = wsb + off;
    off = (off + bytes + 255) & ~(size_t)255;
    return p;
  };
  u16*  xbf  = (u16*)alloc((size_t)T_ * B_ * DIN * 2);
  u16*  hs   = (u16*)alloc((size_t)(T_ + 1) * B_ * H_ * 2);
  u16*  Wg   = (u16*)alloc((size_t)G4 * 384 * 2);
  float* bb  = (float*)alloc(G4 * 4);
  float* Wkp = (float*)alloc((size_t)E_ * H_ * 4);
  float* Wvp = (float*)alloc((size_t)E_ * H_ * 4);
  float* bkp = (float*)alloc(E_ * 4);
  float* bvp = (float*)alloc(E_ * 4);
  float* WuT = (float*)alloc((size_t)E_ * H_ * 4);
  float* bu  = (float*)alloc(H_ * 4);
  float* wd  = (float*)alloc(E_ * 4);
  float* ddp = (float*)alloc(256);
  float* Wovt= (float*)alloc((size_t)H_ * E_ * 4);
  float* bov = (float*)alloc(E_ * 4);
  float* uu  = (float*)alloc((size_t)B_ * H_ * 4);
  float* dvec= (float*)alloc(B_ * 4);
  float* wv  = (float*)alloc((size_t)B_ * H_ * 4);
  float* mst = (float*)alloc((size_t)B_ * DM * 4);
  float* qf  = (float*)alloc((size_t)B_ * 10 * 4);
  float* uw  = (float*)alloc(40 * 8 * 4);
  float* W1t = (float*)alloc((size_t)KMLP * NL1 * 4);
  u32*  cnt  = (u32*)alloc(512 * 4);
  (void)ws_size; (void)in_sizes; (void)n_in; (void)out_size;

  hipLaunchKernelGGL(k_prep1, dim3(9241), dim3(256), 0, stream,
                     lstm_s, W_ih, W_hh, b_ih, b_hh, ipw, ipb, projb, qw, W1,
                     xbf, hs, Wg, bb, W1t, uw, bkp, bvp, cnt);
  hipLaunchKernelGGL(k_prep2, dim3(640), dim3(256), 0, stream, ipw, projW, Wkp, Wvp);
  hipLaunchKernelGGL(k_prep3, dim3(577), dim3(256), 0, stream,
                     ipw, ipb, opw, opb, Wkp, Wvp, bkp, bvp, WuT, bu, wd, ddp, Wovt, bov);

  LstmArgs la;
  la.xbf = xbf; la.hs = hs; la.Wg = Wg; la.bb = bb; la.cnt = cnt;
  void* kargs[] = { (void*)&la };
  hipError_t ce = hipLaunchCooperativeKernel(reinterpret_cast<const void*>(&k_lstm),
                                             dim3(256), dim3(256), kargs, 0, stream);
  if (ce != hipSuccess) {
    // fallback: plain launch (256 blocks on 256 CUs co-schedule in practice)
    hipLaunchKernelGGL(k_lstm, dim3(256), dim3(256), 0, stream, la);
  }

  hipLaunchKernelGGL(k_u,   dim3(512), dim3(256), 0, stream, hs, s, WuT, bu, wd, ddp, uu, dvec);
  hipLaunchKernelGGL(k_aw,  dim3(512), dim3(256), 0, stream, hs, uu, dvec, wv);
  hipLaunchKernelGGL(k_ao,  dim3(512), dim3(384), 0, stream, wv, Wovt, bov, s, mst);
  hipLaunchKernelGGL(k_vqc, dim3(512), dim3(256), 0, stream, mst, uw, qf);
  hipLaunchKernelGGL(k_mlp, dim3(512), dim3(256), 0, stream, mst, qf, W1t, b1, W2, b2, out);
}

// Round 5
// 1326.195 us; speedup vs baseline: 2.7274x; 1.3110x over previous
//
#include <hip/hip_runtime.h>
#include <hip/hip_bf16.h>
#include <math.h>

typedef unsigned int u32;
typedef unsigned long long u64;
typedef unsigned short u16;
typedef __attribute__((ext_vector_type(8))) short short8;
typedef __attribute__((ext_vector_type(4))) float f32x4;
typedef __attribute__((ext_vector_type(4))) int v4i;

#define PI_F 3.14159265358979f
#define B_   512
#define T_   256
#define DIN  128
#define H_   256
#define G4   1024
#define F_   64
#define E_   320
#define DM   384
#define NL1  512
#define NACT 8
#define KMLP 394

// Raw buffer intrinsics (CK idiom): compiler-known memory ops (auto waitcnt,
// free pipelining) with explicit cache policy. aux=17 = sc0|sc1: bypass
// L1+L2, read/write at the device coherence point (MALL) — same semantics
// as agent-scope atomics (R2-proven) but pipelined instead of serialized.
__device__ v4i llvm_amdgcn_raw_buffer_load_v4i32(v4i rsrc, int voffset,
                                                 int soffset, int aux)
    __asm("llvm.amdgcn.raw.buffer.load.v4i32");
__device__ void llvm_amdgcn_raw_buffer_store_i32(int vdata, v4i rsrc,
                                                 int voffset, int soffset,
                                                 int aux)
    __asm("llvm.amdgcn.raw.buffer.store.i32");

__device__ __forceinline__ v4i make_srd(const void* p) {
  v4i r;
  r.x = (int)(u32)(u64)p;
  r.y = (int)(u32)((u64)p >> 32);   // base hi, stride=0
  r.z = (int)0xFFFFFFFFu;           // num_records: bounds check disabled
  r.w = 0x00020000;                 // raw untyped dword access
  return r;
}

__device__ __forceinline__ float b2f(u16 h) {
  union { u32 u; float f; } v; v.u = ((u32)h) << 16; return v.f;
}
__device__ __forceinline__ u16 f2b(float f) {
  union { float f; u32 u; } v; v.f = f;
  u32 r = (v.u + 0x7FFFu + ((v.u >> 16) & 1u)) >> 16;
  return (u16)r;
}
__device__ __forceinline__ float sigf(float x) { return 1.0f / (1.0f + __expf(-x)); }
__device__ __forceinline__ float tanhfast(float x) { return 2.0f / (1.0f + __expf(-2.0f * x)) - 1.0f; }
__device__ __forceinline__ float2 cmul(float2 a, float2 b) {
  return make_float2(a.x * b.x - a.y * b.y, a.x * b.y + a.y * b.x);
}
__device__ __forceinline__ float2 cadd(float2 a, float2 b) {
  return make_float2(a.x + b.x, a.y + b.y);
}

// ---------------------------------------------------------------------------
// prep1: x transpose+bf16, Wg=[W_ih|W_hh] bf16, zero hs[0], W1t, bb, uw, bkp,
// bvp, zero barrier counters
// ---------------------------------------------------------------------------
__global__ void k_prep1(const float* __restrict__ lstm_s,
                        const float* __restrict__ W_ih,
                        const float* __restrict__ W_hh,
                        const float* __restrict__ b_ih,
                        const float* __restrict__ b_hh,
                        const float* __restrict__ ipw,
                        const float* __restrict__ ipb,
                        const float* __restrict__ projb,
                        const float* __restrict__ qw,
                        const float* __restrict__ W1,
                        u16* __restrict__ xbf,
                        u16* __restrict__ hs,
                        u16* __restrict__ Wg,
                        float* __restrict__ bb,
                        float* __restrict__ W1t,
                        float* __restrict__ uw,
                        float* __restrict__ bkp,
                        float* __restrict__ bvp,
                        u32* __restrict__ cnt) {
  const int bid = blockIdx.x;
  const int tid = threadIdx.x;
  if (bid < 8192) {                       // lstm_s (B,T,128) -> xbf (T,B,128) bf16
    u32 u = (u32)bid * 256u + tid;        // < 2097152 uint4 units
    u32 c8 = u & 15u, b = (u >> 4) & 511u, t = u >> 13;
    const float* src = lstm_s + ((size_t)b * T_ + t) * DIN + c8 * 8;
    union { u16 h[8]; uint4 v; } tmp;
#pragma unroll
    for (int i = 0; i < 8; ++i) tmp.h[i] = f2b(src[i]);
    *(uint4*)(xbf + ((size_t)t * B_ + b) * DIN + c8 * 8) = tmp.v;
  } else if (bid < 8384) {                // Wg (1024 x 384) bf16
    u32 u = (u32)(bid - 8192) * 256u + tid;  // < 49152
    u32 c8 = u % 48u, r = u / 48u;
    const float* src = (c8 < 16) ? (W_ih + (size_t)r * DIN + c8 * 8)
                                 : (W_hh + (size_t)r * H_ + (c8 - 16) * 8);
    union { u16 h[8]; uint4 v; } tmp;
#pragma unroll
    for (int i = 0; i < 8; ++i) tmp.h[i] = f2b(src[i]);
    *(uint4*)(Wg + (size_t)r * 384 + c8 * 8) = tmp.v;
  } else if (bid < 8448) {                // zero hs[0]
    u32 u = (u32)(bid - 8384) * 256u + tid;  // < 16384
    ((uint4*)hs)[u] = make_uint4(0, 0, 0, 0);
  } else if (bid < 9236) {                // W1t[k][n] = W1[n][k]
    u32 u = (u32)(bid - 8448) * 256u + tid;  // < 201728
    u32 k = u / 512u, nn = u % 512u;
    W1t[u] = W1[(size_t)nn * KMLP + k];
  } else if (bid == 9236) {               // bb, cnt, uw
    for (int i = tid; i < 1024; i += 256) bb[i] = b_ih[i] + b_hh[i];
    for (int i = tid; i < 1024; i += 256) cnt[i] = 0u;
    if (tid < 40) {
      float w0 = qw[tid * 3 + 0], w1 = qw[tid * 3 + 1], w2 = qw[tid * 3 + 2];
      float c0 = cosf(0.5f * w0), s0 = sinf(0.5f * w0);
      float c1 = cosf(0.5f * w1), s1 = sinf(0.5f * w1);
      float c2 = cosf(0.5f * w2), s2 = sinf(0.5f * w2);
      float2 e0m = make_float2(c0, -s0), e0p = make_float2(c0, s0);
      float2 e2m = make_float2(c2, -s2), e2p = make_float2(c2, s2);
      // T1 = RY(w1) @ RZ(w0)
      float2 t00 = make_float2(c1 * e0m.x, c1 * e0m.y);
      float2 t01 = make_float2(-s1 * e0p.x, -s1 * e0p.y);
      float2 t10 = make_float2(s1 * e0m.x, s1 * e0m.y);
      float2 t11 = make_float2(c1 * e0p.x, c1 * e0p.y);
      // U = RZ(w2) @ T1
      float2 u00 = cmul(e2m, t00), u01 = cmul(e2m, t01);
      float2 u10 = cmul(e2p, t10), u11 = cmul(e2p, t11);
      float* o = uw + tid * 8;
      o[0] = u00.x; o[1] = u00.y; o[2] = u01.x; o[3] = u01.y;
      o[4] = u10.x; o[5] = u10.y; o[6] = u11.x; o[7] = u11.y;
    }
  } else if (bid <= 9238) {               // bkp = Wk @ proj_b + bk
    int o = (bid - 9237) * 256 + tid;
    if (o < E_) {
      float acc = ipb[E_ + o];
      for (int e = 0; e < E_; ++e) acc += ipw[(size_t)(E_ + o) * E_ + e] * projb[e];
      bkp[o] = acc;
    }
  } else {                                // bvp = Wv @ proj_b + bv
    int o = (bid - 9239) * 256 + tid;
    if (o < E_) {
      float acc = ipb[2 * E_ + o];
      for (int e = 0; e < E_; ++e) acc += ipw[(size_t)(2 * E_ + o) * E_ + e] * projb[e];
      bvp[o] = acc;
    }
  }
}

// ---------------------------------------------------------------------------
// prep2: Wk' = Wk @ proj_W, Wv' = Wv @ proj_W  (each 320x256)
// ---------------------------------------------------------------------------
__global__ void k_prep2(const float* __restrict__ ipw, const float* __restrict__ projW,
                        float* __restrict__ Wkp, float* __restrict__ Wvp) {
  int bid = blockIdx.x, tid = threadIdx.x;
  int o = (bid < 320) ? bid : (bid - 320);
  const float* wrow = ipw + (size_t)((bid < 320 ? E_ : 2 * E_) + o) * E_;
  float acc = 0.f;
  for (int e = 0; e < E_; ++e) acc += wrow[e] * projW[(size_t)e * H_ + tid];
  (bid < 320 ? Wkp : Wvp)[(size_t)o * H_ + tid] = acc;
}

// ---------------------------------------------------------------------------
// prep3: WuT[e][j] = sum_o Wkp[o][j]*Wq[o][e];  Wovt[j][i] = sum_o Wo[i][o]*Wvp[o][j]
// plus bu, wd, dd, bov
// ---------------------------------------------------------------------------
__global__ void k_prep3(const float* __restrict__ ipw, const float* __restrict__ ipb,
                        const float* __restrict__ opw, const float* __restrict__ opb,
                        const float* __restrict__ Wkp, const float* __restrict__ Wvp,
                        const float* __restrict__ bkp, const float* __restrict__ bvp,
                        float* __restrict__ WuT, float* __restrict__ bu,
                        float* __restrict__ wd, float* __restrict__ ddp,
                        float* __restrict__ Wovt, float* __restrict__ bov) {
  int bid = blockIdx.x, tid = threadIdx.x;
  if (bid < 320) {
    int e = bid;
    float acc = 0.f;
    for (int o = 0; o < E_; ++o) acc += Wkp[(size_t)o * H_ + tid] * ipw[(size_t)o * E_ + e];
    WuT[(size_t)e * H_ + tid] = acc;
  } else if (bid < 576) {
    int jj = bid - 320;
    for (int i = tid; i < E_; i += 256) {
      float acc = 0.f;
      for (int o = 0; o < E_; ++o) acc += opw[(size_t)i * E_ + o] * Wvp[(size_t)o * H_ + jj];
      Wovt[(size_t)jj * E_ + i] = acc;
    }
  } else {
    {
      float acc = 0.f;
      for (int o = 0; o < E_; ++o) acc += Wkp[(size_t)o * H_ + tid] * ipb[o];
      bu[tid] = acc;
    }
    for (int idx = tid; idx < E_; idx += 256) {
      float a1 = 0.f, a2 = opb[idx];
      for (int o = 0; o < E_; ++o) {
        a1 += ipw[(size_t)o * E_ + idx] * bkp[o];
        a2 += opw[(size_t)idx * E_ + o] * bvp[o];
      }
      wd[idx] = a1; bov[idx] = a2;
    }
    if (tid == 0) {
      float acc = 0.f;
      for (int o = 0; o < E_; ++o) acc += ipb[o] * bkp[o];
      ddp[0] = acc;
    }
  }
}

// ---------------------------------------------------------------------------
// LSTM persistent kernel. 256 blocks = 8 batch-groups(64 rows) x 32 n-slices
// (static mapping, R2-proven). Cross-XCD h handoff via NON-ATOMIC buffer
// ops with aux=17 (sc0|sc1 -> coherence point), which pipeline 8-deep
// (vs R2's serialized atomic u64 loads, ~3us/step). Barrier: __syncthreads
// (implicit vmcnt(0) drains h stores + x prefetch) + agent-scope counter.
// ---------------------------------------------------------------------------
struct LstmArgs {
  const u16* xbf; u16* hs; const u16* Wg; const float* bb; u32* cnt;
};

__launch_bounds__(256, 1)
__global__ void k_lstm(LstmArgs A) {
  const int g   = blockIdx.x & 7;
  const int n   = blockIdx.x >> 3;            // 0..31
  const int tid = threadIdx.x;
  const int wid = tid >> 6, lane = tid & 63;
  __shared__ __align__(16) u16 Wl[32 * 392];  // 32 gate rows x 384 K, pad to 392

  for (int idx = tid; idx < 32 * 48; idx += 256) {
    int ln = idx / 48, c8 = idx % 48;
    int gr = (ln >> 3) * 256 + n * 8 + (ln & 7);
    *(uint4*)&Wl[ln * 392 + c8 * 8] = *(const uint4*)&A.Wg[(size_t)gr * 384 + c8 * 8];
  }
  const int j  = lane & 7;
  const int gc = n * 8 + j;
  const float bbi = A.bb[gc], bbf2 = A.bb[256 + gc];
  const float bbg = A.bb[512 + gc], bbo = A.bb[768 + gc];

  const int quad = lane >> 4;
  const int mrow = lane & 15;
  const int brow = g * 64 + wid * 16 + mrow;
  const int erow0 = g * 64 + wid * 16 + quad * 4;
  const bool hi = (lane & 8) != 0;
  float crs[4] = {0.f, 0.f, 0.f, 0.f};
  u32* mycnt = A.cnt + g * 64;
  u32 target = 0;

  const v4i hs_srd = make_srd(A.hs);
  const int hvoff = (brow * H_ + quad * 8) * 2;   // per-lane byte offset in a step-block

  // prologue: x[0]
  uint4 xc0, xc1, xc2, xc3, xn0, xn1, xn2, xn3;
  {
    const u16* xb = A.xbf + ((size_t)0 * B_ + brow) * DIN + quad * 8;
    xc0 = *(const uint4*)(xb + 0);
    xc1 = *(const uint4*)(xb + 32);
    xc2 = *(const uint4*)(xb + 64);
    xc3 = *(const uint4*)(xb + 96);
  }
  __syncthreads();  // Wl staged

  for (int t = 0; t < T_; ++t) {
    // h_t loads: coherent (sc0|sc1) pipelined buffer loads
    const int hsoff = t * (B_ * H_ * 2);
    uint4 h0 = __builtin_bit_cast(uint4, llvm_amdgcn_raw_buffer_load_v4i32(hs_srd, hvoff +   0, hsoff, 17));
    uint4 h1 = __builtin_bit_cast(uint4, llvm_amdgcn_raw_buffer_load_v4i32(hs_srd, hvoff +  64, hsoff, 17));
    uint4 h2 = __builtin_bit_cast(uint4, llvm_amdgcn_raw_buffer_load_v4i32(hs_srd, hvoff + 128, hsoff, 17));
    uint4 h3 = __builtin_bit_cast(uint4, llvm_amdgcn_raw_buffer_load_v4i32(hs_srd, hvoff + 192, hsoff, 17));
    uint4 h4 = __builtin_bit_cast(uint4, llvm_amdgcn_raw_buffer_load_v4i32(hs_srd, hvoff + 256, hsoff, 17));
    uint4 h5 = __builtin_bit_cast(uint4, llvm_amdgcn_raw_buffer_load_v4i32(hs_srd, hvoff + 320, hsoff, 17));
    uint4 h6 = __builtin_bit_cast(uint4, llvm_amdgcn_raw_buffer_load_v4i32(hs_srd, hvoff + 384, hsoff, 17));
    uint4 h7 = __builtin_bit_cast(uint4, llvm_amdgcn_raw_buffer_load_v4i32(hs_srd, hvoff + 448, hsoff, 17));
    // x[t+1] prefetch (plain cached loads; drained by the barrier's vmcnt(0))
    {
      const int tn = (t + 1 < T_) ? (t + 1) : t;
      const u16* xb = A.xbf + ((size_t)tn * B_ + brow) * DIN + quad * 8;
      xn0 = *(const uint4*)(xb + 0);
      xn1 = *(const uint4*)(xb + 32);
      xn2 = *(const uint4*)(xb + 64);
      xn3 = *(const uint4*)(xb + 96);
    }

    f32x4 acc0 = {0.f, 0.f, 0.f, 0.f}, acc1 = {0.f, 0.f, 0.f, 0.f};
#define MMSTEP(AV, KOFF)                                                          \
    {                                                                             \
      short8 av  = __builtin_bit_cast(short8, AV);                                \
      short8 bv0 = __builtin_bit_cast(short8,                                     \
          *(const uint4*)&Wl[mrow * 392 + (KOFF) + quad * 8]);                    \
      short8 bv1 = __builtin_bit_cast(short8,                                     \
          *(const uint4*)&Wl[(16 + mrow) * 392 + (KOFF) + quad * 8]);             \
      acc0 = __builtin_amdgcn_mfma_f32_16x16x32_bf16(av, bv0, acc0, 0, 0, 0);     \
      acc1 = __builtin_amdgcn_mfma_f32_16x16x32_bf16(av, bv1, acc1, 0, 0, 0);     \
    }
    MMSTEP(xc0, 0)   MMSTEP(xc1, 32)  MMSTEP(xc2, 64)  MMSTEP(xc3, 96)
    MMSTEP(h0, 128)  MMSTEP(h1, 160)  MMSTEP(h2, 192)  MMSTEP(h3, 224)
    MMSTEP(h4, 256)  MMSTEP(h5, 288)  MMSTEP(h6, 320)  MMSTEP(h7, 352)
#undef MMSTEP

    // epilogue: lanes bit3=0 hold i (tile0) & g (tile1); bit3=1 hold f & o
    const int hsoff_o = (t + 1) * (B_ * H_ * 2);
#pragma unroll
    for (int r = 0; r < 4; ++r) {
      float x0 = acc0[r], x1v = acc1[r];
      float y0 = __shfl_xor(x0, 8, 64);
      float y1 = __shfl_xor(x1v, 8, 64);
      float iv = (hi ? y0 : x0) + bbi;
      float fv = (hi ? x0 : y0) + bbf2;
      float gv = (hi ? y1 : x1v) + bbg;
      float ov = (hi ? x1v : y1) + bbo;
      float cc = sigf(fv) * crs[r] + sigf(iv) * tanhfast(gv);
      crs[r] = cc;
      float hh = sigf(ov) * tanhfast(cc);
      float hh2 = __shfl_xor(hh, 1, 64);      // partner column's h
      if (!hi && ((j & 1) == 0)) {
        u32 pk = (u32)f2b(hh) | ((u32)f2b(hh2) << 16);
        llvm_amdgcn_raw_buffer_store_i32((int)pk, hs_srd,
                                         ((erow0 + r) * H_ + gc) * 2, hsoff_o, 17);
      }
    }
    // ---- group barrier (release h_t, acquire peers' h_t) ----
    target += 32;
    if (t != T_ - 1) {
      __syncthreads();   // implicit vmcnt(0): h stores at MALL, x prefetch done
      if (tid == 0) {
        __hip_atomic_fetch_add(mycnt, 1u, __ATOMIC_RELAXED, __HIP_MEMORY_SCOPE_AGENT);
        int guard = 0;
        while (__hip_atomic_load(mycnt, __ATOMIC_RELAXED, __HIP_MEMORY_SCOPE_AGENT) < target) {
          __builtin_amdgcn_s_sleep(1);
          if (++guard > (1 << 24)) break;
        }
      }
      __syncthreads();
      xc0 = xn0; xc1 = xn1; xc2 = xn2; xc3 = xn3;
    }
  }
}

// ---------------------------------------------------------------------------
// k_u: u_b = WuT^T-style matvec on z=[h_T, s];  d_b = wd.z + dd
// ---------------------------------------------------------------------------
__global__ void k_u(const u16* __restrict__ hs, const float* __restrict__ s,
                    const float* __restrict__ WuT, const float* __restrict__ bu,
                    const float* __restrict__ wd, const float* __restrict__ ddp,
                    float* __restrict__ u, float* __restrict__ dvec) {
  int b = blockIdx.x, tid = threadIdx.x;
  __shared__ float z[E_];
  __shared__ float red[256];
  z[tid] = b2f(hs[((size_t)T_ * B_ + b) * H_ + tid]);
  if (tid < F_) z[H_ + tid] = s[(size_t)b * F_ + tid];
  __syncthreads();
  float acc = bu[tid];
  for (int e = 0; e < E_; ++e) acc += WuT[(size_t)e * H_ + tid] * z[e];
  u[(size_t)b * H_ + tid] = acc;
  float p = 0.f;
  for (int e = tid; e < E_; e += 256) p += wd[e] * z[e];
  red[tid] = p;
  __syncthreads();
  for (int s2 = 128; s2 > 0; s2 >>= 1) {
    if (tid < s2) red[tid] += red[tid + s2];
    __syncthreads();
  }
  if (tid == 0) dvec[b] = red[0] + ddp[0];
}

// ---------------------------------------------------------------------------
// k_aw: scores -> softmax -> w_b = sum_t attn_t * h_t   (block per batch row)
// ---------------------------------------------------------------------------
__global__ void k_aw(const u16* __restrict__ hs, const float* __restrict__ u,
                     const float* __restrict__ dvec, float* __restrict__ wv) {
  int b = blockIdx.x, tid = threadIdx.x;
  int wid = tid >> 6, lane = tid & 63;
  __shared__ float sc[T_];
  __shared__ float red[256];
  const float db = dvec[b];
  const float scale = 0.055901699437494745f;  // 1/sqrt(320)
  float4 ul = *(const float4*)&u[(size_t)b * H_ + lane * 4];
  for (int tt = 0; tt < 64; ++tt) {
    int t = wid * 64 + tt;
    u32 rw0 = ((const u32*)(hs + ((size_t)(t + 1) * B_ + b) * H_))[lane * 2];
    u32 rw1 = ((const u32*)(hs + ((size_t)(t + 1) * B_ + b) * H_))[lane * 2 + 1];
    union { u32 uu; float f; } f0, f1, f2, f3;
    f0.uu = rw0 << 16; f1.uu = rw0 & 0xFFFF0000u;
    f2.uu = rw1 << 16; f3.uu = rw1 & 0xFFFF0000u;
    float p = f0.f * ul.x + f1.f * ul.y + f2.f * ul.z + f3.f * ul.w;
#pragma unroll
    for (int off = 32; off > 0; off >>= 1) p += __shfl_xor(p, off, 64);
    if (lane == 0) sc[t] = (p + db) * scale;
  }
  __syncthreads();
  float v = sc[tid];
  red[tid] = v;
  __syncthreads();
  for (int s2 = 128; s2 > 0; s2 >>= 1) {
    if (tid < s2) red[tid] = fmaxf(red[tid], red[tid + s2]);
    __syncthreads();
  }
  float m = red[0];
  __syncthreads();
  float e = __expf(v - m);
  red[tid] = e;
  __syncthreads();
  for (int s2 = 128; s2 > 0; s2 >>= 1) {
    if (tid < s2) red[tid] += red[tid + s2];
    __syncthreads();
  }
  float inv = 1.f / red[0];
  __syncthreads();
  sc[tid] = e * inv;
  __syncthreads();
  float acc = 0.f;
#pragma unroll 8
  for (int t = 0; t < T_; ++t) {
    acc += sc[t] * b2f(hs[((size_t)(t + 1) * B_ + b) * H_ + tid]);
  }
  wv[(size_t)b * H_ + tid] = acc;
}

// ---------------------------------------------------------------------------
// k_ao: merged_state = [Wov @ w_b + bov, s_b]
// ---------------------------------------------------------------------------
__global__ void k_ao(const float* __restrict__ wv, const float* __restrict__ Wovt,
                     const float* __restrict__ bov, const float* __restrict__ s,
                     float* __restrict__ mst) {
  int b = blockIdx.x, tid = threadIdx.x;
  __shared__ float wl[H_];
  if (tid < H_) wl[tid] = wv[(size_t)b * H_ + tid];
  __syncthreads();
  if (tid < E_) {
    float acc = bov[tid];
    for (int jj = 0; jj < H_; ++jj) acc += Wovt[(size_t)jj * E_ + tid] * wl[jj];
    mst[(size_t)b * DM + tid] = acc;
  } else if (tid < DM) {
    mst[(size_t)b * DM + tid] = s[(size_t)b * F_ + (tid - E_)];
  }
}

// ---------------------------------------------------------------------------
// k_vqc: 10-qubit statevector sim; 1 combined gate per (layer,qubit); psi in LDS
// ---------------------------------------------------------------------------
__global__ void k_vqc(const float* __restrict__ mst, const float* __restrict__ uwg,
                      float* __restrict__ qf) {
  int b = blockIdx.x, tid = threadIdx.x;
  __shared__ float2 psi[1024];
  __shared__ float ang[40];
  __shared__ float uwl[320];
  __shared__ float part[4][10];
  if (tid < 40) ang[tid] = tanhf(mst[(size_t)b * DM + tid]) * PI_F;
  uwl[tid] = uwg[tid];
  if (tid < 64) uwl[256 + tid] = uwg[256 + tid];
#pragma unroll
  for (int k = 0; k < 4; ++k) psi[tid + k * 256] = make_float2(0.03125f, 0.f);
  __syncthreads();
  for (int l = 0; l < 4; ++l) {
    for (int q = 0; q < 10; ++q) {
      int lq = l * 10 + q;
      float a = ang[lq];
      float ca = __cosf(0.5f * a), sa = __sinf(0.5f * a);
      float cs = ca * sa;
      float2 m00 = make_float2(ca * ca, sa * sa);
      float2 m01 = make_float2(-cs, -cs);
      float2 m10 = make_float2(cs, -cs);
      float2 m11 = make_float2(ca * ca, -sa * sa);
      const float* uwp = &uwl[lq * 8];
      float2 a00 = make_float2(uwp[0], uwp[1]), a01 = make_float2(uwp[2], uwp[3]);
      float2 a10 = make_float2(uwp[4], uwp[5]), a11 = make_float2(uwp[6], uwp[7]);
      float2 u00 = cadd(cmul(a00, m00), cmul(a01, m10));
      float2 u01 = cadd(cmul(a00, m01), cmul(a01, m11));
      float2 u10 = cadd(cmul(a10, m00), cmul(a11, m10));
      float2 u11 = cadd(cmul(a10, m01), cmul(a11, m11));
      int bp = 9 - q;
      __syncthreads();
#pragma unroll
      for (int k = 0; k < 2; ++k) {
        int p = tid + k * 256;
        int i0 = ((p >> bp) << (bp + 1)) | (p & ((1 << bp) - 1));
        int i1 = i0 | (1 << bp);
        float2 A0 = psi[i0], A1 = psi[i1];
        psi[i0] = cadd(cmul(u00, A0), cmul(u01, A1));
        psi[i1] = cadd(cmul(u10, A0), cmul(u11, A1));
      }
    }
    for (int q = 0; q < 9; ++q) {  // CNOT(q, q+1): adjacent bits
      int lo = 8 - q;
      __syncthreads();
      int p = tid;
      int i0 = ((p >> lo) << (lo + 2)) | (2 << lo) | (p & ((1 << lo) - 1));
      int i1 = i0 | (1 << lo);
      float2 tmp = psi[i0]; psi[i0] = psi[i1]; psi[i1] = tmp;
    }
    __syncthreads();  // CNOT(9, 0): ctrl bit0, tgt bit9
    {
      int i0 = (tid << 1) | 1;
      int i1 = i0 | 512;
      float2 tmp = psi[i0]; psi[i0] = psi[i1]; psi[i1] = tmp;
    }
  }
  __syncthreads();
  float acc[10];
#pragma unroll
  for (int q = 0; q < 10; ++q) acc[q] = 0.f;
#pragma unroll
  for (int k = 0; k < 4; ++k) {
    int idx = tid + k * 256;
    float2 A = psi[idx];
    float pr = A.x * A.x + A.y * A.y;
#pragma unroll
    for (int q = 0; q < 10; ++q) acc[q] += ((idx >> (9 - q)) & 1) ? -pr : pr;
  }
  int lane = tid & 63, wid = tid >> 6;
#pragma unroll
  for (int q = 0; q < 10; ++q) {
    float vq = acc[q];
#pragma unroll
    for (int off = 32; off > 0; off >>= 1) vq += __shfl_xor(vq, off, 64);
    if (lane == 0) part[wid][q] = vq;
  }
  __syncthreads();
  if (tid < 10) qf[(size_t)b * 10 + tid] = part[0][tid] + part[1][tid] + part[2][tid] + part[3][tid];
}

// ---------------------------------------------------------------------------
// k_mlp: x1 = relu([mst,qf] @ W1^T + b1); out = x1 @ W2^T + b2
// ---------------------------------------------------------------------------
__global__ void k_mlp(const float* __restrict__ mst, const float* __restrict__ qf,
                      const float* __restrict__ W1t, const float* __restrict__ b1,
                      const float* __restrict__ W2, const float* __restrict__ b2,
                      float* __restrict__ out) {
  int b = blockIdx.x, tid = threadIdx.x;
  __shared__ float mg[KMLP];
  __shared__ float x1[NL1];
  __shared__ float red[256];
  for (int i = tid; i < DM; i += 256) mg[i] = mst[(size_t)b * DM + i];
  if (tid < 10) mg[DM + tid] = qf[(size_t)b * 10 + tid];
  __syncthreads();
#pragma unroll
  for (int hh = 0; hh < 2; ++hh) {
    int nn = tid + hh * 256;
    float acc = b1[nn];
#pragma unroll 4
    for (int k = 0; k < KMLP; ++k) acc += W1t[(size_t)k * NL1 + nn] * mg[k];
    x1[nn] = fmaxf(acc, 0.f);
  }
  __syncthreads();
  int a = tid >> 5, l32 = tid & 31;
  float p = 0.f;
  for (int k = l32; k < NL1; k += 32) p += x1[k] * W2[(size_t)a * NL1 + k];
  red[tid] = p;
  __syncthreads();
  if (tid < 8) {
    float acc = b2[tid];
#pragma unroll
    for (int i = 0; i < 32; ++i) acc += red[tid * 32 + i];
    out[(size_t)b * NACT + tid] = acc;
  }
}

// ---------------------------------------------------------------------------
extern "C" void kernel_launch(void* const* d_in, const int* in_sizes, int n_in,
                              void* d_out, int out_size, void* d_ws, size_t ws_size,
                              hipStream_t stream) {
  const float* s      = (const float*)d_in[0];
  const float* lstm_s = (const float*)d_in[1];
  const float* W_ih   = (const float*)d_in[2];
  const float* W_hh   = (const float*)d_in[3];
  const float* b_ih   = (const float*)d_in[4];
  const float* b_hh   = (const float*)d_in[5];
  const float* projW  = (const float*)d_in[6];
  const float* projb  = (const float*)d_in[7];
  const float* ipw    = (const float*)d_in[8];
  const float* ipb    = (const float*)d_in[9];
  const float* opw    = (const float*)d_in[10];
  const float* opb    = (const float*)d_in[11];
  const float* qw     = (const float*)d_in[12];
  const float* W1     = (const float*)d_in[13];
  const float* b1     = (const float*)d_in[14];
  const float* W2     = (const float*)d_in[15];
  const float* b2     = (const float*)d_in[16];
  float* out = (float*)d_out;

  char* wsb = (char*)d_ws;
  size_t off = 0;
  auto alloc = [&](size_t bytes) -> void* {
    void* p = wsb + off;
    off = (off + bytes + 255) & ~(size_t)255;
    return p;
  };
  u16*  xbf  = (u16*)alloc((size_t)T_ * B_ * DIN * 2);
  u16*  hs   = (u16*)alloc((size_t)(T_ + 1) * B_ * H_ * 2);
  u16*  Wg   = (u16*)alloc((size_t)G4 * 384 * 2);
  float* bb  = (float*)alloc(G4 * 4);
  float* Wkp = (float*)alloc((size_t)E_ * H_ * 4);
  float* Wvp = (float*)alloc((size_t)E_ * H_ * 4);
  float* bkp = (float*)alloc(E_ * 4);
  float* bvp = (float*)alloc(E_ * 4);
  float* WuT = (float*)alloc((size_t)E_ * H_ * 4);
  float* bu  = (float*)alloc(H_ * 4);
  float* wd  = (float*)alloc(E_ * 4);
  float* ddp = (float*)alloc(256);
  float* Wovt= (float*)alloc((size_t)H_ * E_ * 4);
  float* bov = (float*)alloc(E_ * 4);
  float* uu  = (float*)alloc((size_t)B_ * H_ * 4);
  float* dvec= (float*)alloc(B_ * 4);
  float* wv  = (float*)alloc((size_t)B_ * H_ * 4);
  float* mst = (float*)alloc((size_t)B_ * DM * 4);
  float* qf  = (float*)alloc((size_t)B_ * 10 * 4);
  float* uw  = (float*)alloc(40 * 8 * 4);
  float* W1t = (float*)alloc((size_t)KMLP * NL1 * 4);
  u32*  cnt  = (u32*)alloc(1024 * 4);
  (void)ws_size; (void)in_sizes; (void)n_in; (void)out_size;

  hipLaunchKernelGGL(k_prep1, dim3(9241), dim3(256), 0, stream,
                     lstm_s, W_ih, W_hh, b_ih, b_hh, ipw, ipb, projb, qw, W1,
                     xbf, hs, Wg, bb, W1t, uw, bkp, bvp, cnt);
  hipLaunchKernelGGL(k_prep2, dim3(640), dim3(256), 0, stream, ipw, projW, Wkp, Wvp);
  hipLaunchKernelGGL(k_prep3, dim3(577), dim3(256), 0, stream,
                     ipw, ipb, opw, opb, Wkp, Wvp, bkp, bvp, WuT, bu, wd, ddp, Wovt, bov);

  LstmArgs la;
  la.xbf = xbf; la.hs = hs; la.Wg = Wg; la.bb = bb; la.cnt = cnt;
  void* kargs[] = { (void*)&la };
  hipError_t ce = hipLaunchCooperativeKernel(reinterpret_cast<const void*>(&k_lstm),
                                             dim3(256), dim3(256), kargs, 0, stream);
  if (ce != hipSuccess) {
    // fallback: plain launch (256 blocks on 256 CUs co-schedule in practice)
    hipLaunchKernelGGL(k_lstm, dim3(256), dim3(256), 0, stream, la);
  }

  hipLaunchKernelGGL(k_u,   dim3(512), dim3(256), 0, stream, hs, s, WuT, bu, wd, ddp, uu, dvec);
  hipLaunchKernelGGL(k_aw,  dim3(512), dim3(256), 0, stream, hs, uu, dvec, wv);
  hipLaunchKernelGGL(k_ao,  dim3(512), dim3(384), 0, stream, wv, Wovt, bov, s, mst);
  hipLaunchKernelGGL(k_vqc, dim3(512), dim3(256), 0, stream, mst, uw, qf);
  hipLaunchKernelGGL(k_mlp, dim3(512), dim3(256), 0, stream, mst, qf, W1t, b1, W2, b2, out);
}